// Round 9
// baseline (228.224 us; speedup 1.0000x reference)
//
#include <hip/hip_runtime.h>
#include <cmath>

#define S_LEN 2048
#define DMODEL 1024
#define NHEADS 16
#define DK 64
#define BATCH 2
#define MTOT (BATCH * S_LEN) /* 4096 */

using short8 = __attribute__((ext_vector_type(8))) short;
using floatx4 = __attribute__((ext_vector_type(4))) float;

// float -> bf16 bits, round-to-nearest-even
__device__ __forceinline__ unsigned short f2b(float f) {
    union { float f; unsigned u; } v; v.f = f;
    unsigned r = v.u + 0x7fff + ((v.u >> 16) & 1);
    return (unsigned short)(r >> 16);
}

// async global->LDS, 16 B/lane. LDS dest is wave-uniform base (+lane*16 by HW).
__device__ __forceinline__ void gload16(const void* g, void* l) {
    __builtin_amdgcn_global_load_lds(
        (const __attribute__((address_space(1))) unsigned int*)g,
        (__attribute__((address_space(3))) unsigned int*)l, 16, 0, 0);
}

// ---------------------------------------------------------------------------
// Fused preprocessing (single dispatch, blockIdx-range partition):
//   blocks [0, 2048)        : x fp32 -> bf16 cast
//   blocks [2048, 2304)     : RoPE cos/sin tables
//   blocks [2304, 3328)     : W fp32 [k][n] -> bf16 [n][k] transpose
//                             (Wq,Wk head-dims permuted: d -> d/2 or 32+d/2)
// ---------------------------------------------------------------------------
__global__ __launch_bounds__(256) void prep_k(
    const float* __restrict__ x, unsigned short* __restrict__ xb,
    const int* __restrict__ tokpos, float* __restrict__ ct, float* __restrict__ st,
    const float* W0, const float* W1, const float* W2, const float* W3,
    unsigned short* T0, unsigned short* T1, unsigned short* T2, unsigned short* T3) {
    __shared__ float t[64][65];
    const int b = blockIdx.x;
    if (b < 2048) {
        int i = (b * 256 + threadIdx.x) * 8;
        float4 a = *(const float4*)(x + i);
        float4 bb = *(const float4*)(x + i + 4);
        short8 o;
        o[0] = f2b(a.x); o[1] = f2b(a.y); o[2] = f2b(a.z); o[3] = f2b(a.w);
        o[4] = f2b(bb.x); o[5] = f2b(bb.y); o[6] = f2b(bb.z); o[7] = f2b(bb.w);
        *(short8*)(xb + i) = o;
    } else if (b < 2304) {
        int idx = (b - 2048) * 256 + threadIdx.x;  // 0 .. 2048*32-1
        int si = idx >> 5;
        int ip = idx & 31;
        float pos = (float)tokpos[si];
        float inv_freq = powf(10000.0f, -(float)(2 * ip) / 64.0f);
        float ang = pos * inv_freq;
        ct[idx] = cosf(ang);
        st[idx] = sinf(ang);
    } else {
        int id = b - 2304;          // 0..1023
        int z = id >> 8;            // matrix
        int bx = id & 15, by = (id >> 4) & 15;
        const float* W = z == 0 ? W0 : z == 1 ? W1 : z == 2 ? W2 : W3;
        unsigned short* T = z == 0 ? T0 : z == 1 ? T1 : z == 2 ? T2 : T3;
        const bool perm = (z < 2);
        int n0 = bx * 64, k0 = by * 64;
        int rr = threadIdx.x >> 6, cc = threadIdx.x & 63;
#pragma unroll
        for (int r = 0; r < 16; r++) {
            int row = r * 4 + rr;
            t[row][cc] = W[(size_t)(k0 + row) * DMODEL + n0 + cc];
        }
        __syncthreads();
#pragma unroll
        for (int r = 0; r < 16; r++) {
            int row = r * 4 + rr;  // original col within head
            int drow = perm ? (((row & 1) ? 32 : 0) + (row >> 1)) : row;
            T[(size_t)(n0 + drow) * DMODEL + k0 + cc] = f2b(t[cc][row]);
        }
    }
}

// ---------------------------------------------------------------------------
// bf16 MFMA GEMM: C[4096,1024] = A[4096,1024] x Bt^T  (Bt is [N][K] bf16)
// 128x128 tile, BK=32, 4 waves, 4x4 mfma. Grid (x=m, y=n, z): XCD A-reuse.
// kind 0: z<2 -> RoPE (permuted-d weights, shuffle-free) bf16; Q (z==0)
//   scaled by 1/sqrt(dk)=0.125 folded into cos/sin.
//   z==2 -> TRANSPOSED bf16 store: Vt[b*1024 + n][s] via per-wave LDS bounce
//   (fuses the former vtrans kernel).
// kind 1: plain fp32 store (final output).
// ---------------------------------------------------------------------------
__global__ __launch_bounds__(256) void mm_k(
    const unsigned short* __restrict__ A,
    const unsigned short* __restrict__ Bt0, const unsigned short* __restrict__ Bt1,
    const unsigned short* __restrict__ Bt2,
    void* C0, void* C1, void* C2,
    const float* __restrict__ ct, const float* __restrict__ st, int kind) {
    // bytes [0,8192): A staging; [8192,16384): B staging.
    // mode-3 epilogue reuses the whole array: 4 wave regions x 32 rows x
    // stride 70 shorts (pad -> <=2-way banks) = 8960 shorts.
    __shared__ __align__(16) unsigned short blob[8960];

    const int z = blockIdx.z;
    const unsigned short* Bt = z == 0 ? Bt0 : z == 1 ? Bt1 : Bt2;
    void* C = z == 0 ? C0 : z == 1 ? C1 : C2;
    const int mode = (kind == 1) ? 0 : (z == 2 ? 3 : 1);
    const float qscale = (z == 0 && kind == 0) ? 0.125f : 1.0f;

    const int tid = threadIdx.x;
    const int w = tid >> 6, lane = tid & 63;
    const int l15 = lane & 15, quad = lane >> 4;
    const int wr = w >> 1, wc = w & 1;
    const int m0 = blockIdx.x * 128, n0 = blockIdx.y * 128;  // x=m: XCD A-reuse

    floatx4 acc[4][4];
#pragma unroll
    for (int i = 0; i < 4; i++)
#pragma unroll
        for (int j = 0; j < 4; j++) acc[i][j] = (floatx4){0.f, 0.f, 0.f, 0.f};

    for (int k0 = 0; k0 < DMODEL; k0 += 32) {
        if (k0) __syncthreads();
#pragma unroll
        for (int it = 0; it < 4; it++) {
            int g = it * 4 + w;  // wave-uniform group 0..15 (A: 0..7, B: 8..15)
            const unsigned short* gp;
            if (g < 8)
                gp = A + (size_t)(m0 + g * 16 + l15) * DMODEL + k0 + (lane >> 4) * 8;
            else
                gp = Bt + (size_t)(n0 + (g - 8) * 16 + l15) * DMODEL + k0 + (lane >> 4) * 8;
            gload16(gp, (char*)blob + g * 1024);
        }
        __syncthreads();

        short8 af[4], bfr[4];
#pragma unroll
        for (int i = 0; i < 4; i++)
            af[i] = *(const short8*)((char*)blob + ((wr * 4 + i) * 64 + lane) * 16);
#pragma unroll
        for (int j = 0; j < 4; j++)
            bfr[j] = *(const short8*)((char*)blob + 8192 + ((wc * 4 + j) * 64 + lane) * 16);
#pragma unroll
        for (int i = 0; i < 4; i++)
#pragma unroll
            for (int j = 0; j < 4; j++)
                acc[i][j] = __builtin_amdgcn_mfma_f32_16x16x32_bf16(af[i], bfr[j], acc[i][j], 0, 0, 0);
    }

    // epilogue: C/D layout col = l15, row = quad*4 + reg
    if (mode == 3) {
        // Vt store: transpose each wave's 64x64 block via LDS, two 32-col
        // halves; coalesced 128B-contiguous global rows.
        __syncthreads();  // all waves done reading staging blob
        unsigned short* tw = blob + w * 2240;  // 32 rows x stride 70
        unsigned short* Cb = (unsigned short*)C;
        const int gmb = m0 + wr * 64;       // wave's m (sequence) base
        const int bb2 = gmb >> 11;          // batch
        const int srow0 = gmb & (S_LEN - 1);
#pragma unroll
        for (int jh = 0; jh < 2; jh++) {
#pragma unroll
            for (int jj = 0; jj < 2; jj++) {
                int j = jh * 2 + jj;
                int nl = jj * 16 + l15;  // local n in [0,32)
#pragma unroll
                for (int i = 0; i < 4; i++) {
                    ushort4 pk;
                    pk.x = f2b(acc[i][j][0]);
                    pk.y = f2b(acc[i][j][1]);
                    pk.z = f2b(acc[i][j][2]);
                    pk.w = f2b(acc[i][j][3]);
                    *(ushort4*)(tw + nl * 70 + i * 16 + quad * 4) = pk;
                }
            }
            // wave-local read-back (compiler orders LDS ops within the wave)
            int nl = lane >> 1, mh = (lane & 1) * 32;
            short8 q0 = *(const short8*)(tw + nl * 70 + mh + 0);
            short8 q1 = *(const short8*)(tw + nl * 70 + mh + 8);
            short8 q2 = *(const short8*)(tw + nl * 70 + mh + 16);
            short8 q3 = *(const short8*)(tw + nl * 70 + mh + 24);
            int gn = n0 + wc * 64 + jh * 32 + nl;
            unsigned short* dst = Cb + (size_t)(bb2 * 1024 + gn) * S_LEN + srow0 + mh;
            *(short8*)(dst + 0) = q0;
            *(short8*)(dst + 8) = q1;
            *(short8*)(dst + 16) = q2;
            *(short8*)(dst + 24) = q3;
        }
        return;
    }
#pragma unroll
    for (int i = 0; i < 4; i++) {
        const int rowb = m0 + wr * 64 + i * 16 + quad * 4;
        if (mode == 0) {
            float* Cf = (float*)C;
#pragma unroll
            for (int j = 0; j < 4; j++) {
                int colb = n0 + wc * 64 + j * 16 + l15;
#pragma unroll
                for (int r = 0; r < 4; r++)
                    Cf[(size_t)(rowb + r) * DMODEL + colb] = acc[i][j][r];
            }
        } else {  // mode 1: RoPE bf16 (permuted-d weights)
            unsigned short* Cb = (unsigned short*)C;
#pragma unroll
            for (int jh = 0; jh < 2; jh++) {
                int ip = jh * 16 + l15;                   // pair index within head
                int cole = n0 + wc * 64 + jh * 16 + l15;  // even-member column (d'<32)
#pragma unroll
                for (int r = 0; r < 4; r++) {
                    int row = rowb + r;
                    int si = row & (S_LEN - 1);
                    float c = ct[si * 32 + ip] * qscale;
                    float s = st[si * 32 + ip] * qscale;
                    float e = acc[i][jh][r];       // x_even (permuted weights)
                    float od = acc[i][jh + 2][r];  // x_odd (partner col, same thread)
                    Cb[(size_t)row * DMODEL + cole] = f2b(e * c - od * s);
                    Cb[(size_t)row * DMODEL + cole + 32] = f2b(e * s + od * c);
                }
            }
        }
    }
}

// ---------------------------------------------------------------------------
// Block-cooperative MFMA flash attention, 64-key tiles, 128-query blocks.
// Grid 512 = (16 q-tiles x 32 bh), longest first; 8 waves (512 thr), each
// wave owns 16 queries (R7 config — R8's 32 q/wave regressed: occupancy
// 35->14%). One staged K/V tile feeds 8 waves. Double-buffered LDS via
// global_load_lds, 1 barrier per tile. Q pre-scaled by 1/sqrt(dk).
// S^T = K Q^T -> per-lane softmax (2 shfl max, l deferred), P via per-wave
// LDS -> O^T = V^T P^T.
// ---------------------------------------------------------------------------
__global__ __launch_bounds__(512) void attn_k(const unsigned short* __restrict__ Q,
                                              const unsigned short* __restrict__ K,
                                              const unsigned short* __restrict__ Vt,
                                              unsigned short* __restrict__ O) {
    __shared__ __align__(16) unsigned short Kblob[2][4096];  // 8 KB/buf
    __shared__ __align__(16) unsigned short Vblob[2][4096];
    __shared__ __align__(16) unsigned short Ps[8][16 * 72];  // per-wave P / O-bounce

    const int tid = threadIdx.x;
    const int w = tid >> 6, lane = tid & 63;
    const int l15 = lane & 15, quad = lane >> 4;
    const int idx = blockIdx.x;
    const int qt = 15 - (idx >> 5);  // longest blocks dispatch first
    const int bh = idx & 31;
    const int bb = bh >> 4, h = bh & 15;
    const int qbase = qt * 128 + w * 16;
    const int qrow = qbase + l15;

    // Q fragment (B-operand: col=query=l15, k=quad*8), d-halves 0/1
    const size_t qoff = (size_t)(bb * S_LEN + qbase + l15) * DMODEL + h * DK;
    short8 aq0 = *(const short8*)(Q + qoff + quad * 8);
    short8 aq1 = *(const short8*)(Q + qoff + 32 + quad * 8);

    floatx4 o[4];
#pragma unroll
    for (int f = 0; f < 4; f++) o[f] = (floatx4){0.f, 0.f, 0.f, 0.f};
    float mv = -1e30f, lv = 0.f;

    const unsigned short* Kb = K + (size_t)(bb * S_LEN) * DMODEL + h * DK;
    const unsigned short* Vb = Vt + (size_t)(bb * 1024 + h * DK) * S_LEN;
    unsigned short* ps = &Ps[w][0];

    // stage 64-key K/V tile into blob buffer b (2 gload16/thread, 8 waves)
    auto stage = [&](int b, int kb) {
#pragma unroll
        for (int it = 0; it < 2; it++) {
            int g = it * 8 + w;  // wave-uniform 0..15; 0..7 K-groups, 8..15 V-groups
            if (g < 8) {
                const unsigned short* gp =
                    Kb + (size_t)(kb + (g >> 1) * 16 + l15) * DMODEL + (g & 1) * 32 + quad * 8;
                gload16(gp, (char*)&Kblob[b][0] + g * 1024);
            } else {
                int gv = g - 8;
                const unsigned short* gp =
                    Vb + (size_t)((gv >> 1) * 16 + l15) * S_LEN + kb + (gv & 1) * 32 + quad * 8;
                gload16(gp, (char*)&Vblob[b][0] + gv * 1024);
            }
        }
    };

    const int nkt = 2 * qt + 2;  // key tiles covering 0..qt*128+127, uniform
    stage(0, 0);
    for (int kt = 0; kt < nkt; kt++) {
        const int b = kt & 1;
        const int kb = kt * 64;
        __syncthreads();  // staging of buf b complete; buf b^1 reads done
        if (kt + 1 < nkt) stage(b ^ 1, (kt + 1) * 64);

        // QK^T: S^T[key 64][q 16]
        const unsigned short* kbb = &Kblob[b][0];
        floatx4 c[4];
#pragma unroll
        for (int g = 0; g < 4; g++) {
            short8 kf0 = *(const short8*)(kbb + (g * 2 + 0) * 512 + lane * 8);
            short8 kf1 = *(const short8*)(kbb + (g * 2 + 1) * 512 + lane * 8);
            floatx4 t = {0.f, 0.f, 0.f, 0.f};
            t = __builtin_amdgcn_mfma_f32_16x16x32_bf16(kf0, aq0, t, 0, 0, 0);
            c[g] = __builtin_amdgcn_mfma_f32_16x16x32_bf16(kf1, aq1, t, 0, 0, 0);
        }

        // softmax over 16 keys/lane (scores pre-scaled via Q)
        float sv[16];
#pragma unroll
        for (int g = 0; g < 4; g++)
#pragma unroll
            for (int r = 0; r < 4; r++) {
                int key = kb + g * 16 + quad * 4 + r;
                sv[g * 4 + r] = (key <= qrow) ? c[g][r] : -1e30f;
            }
        float mx = sv[0];
#pragma unroll
        for (int i = 1; i < 16; i++) mx = fmaxf(mx, sv[i]);
        mx = fmaxf(mx, __shfl_xor(mx, 16));
        mx = fmaxf(mx, __shfl_xor(mx, 32));
        float mnew = fmaxf(mv, mx);
        float alpha = __expf(mv - mnew);
        mv = mnew;
        float p[16], psum = 0.f;
#pragma unroll
        for (int i = 0; i < 16; i++) {
            p[i] = __expf(sv[i] - mnew);
            psum += p[i];
        }
        lv = lv * alpha + psum;  // per-lane partial; cross-quad reduce at end

        // P -> LDS (row=q l15, key = g*16+quad*4..+3), stride 72 shorts
#pragma unroll
        for (int g = 0; g < 4; g++) {
            ushort4 pk;
            pk.x = f2b(p[g * 4 + 0]); pk.y = f2b(p[g * 4 + 1]);
            pk.z = f2b(p[g * 4 + 2]); pk.w = f2b(p[g * 4 + 3]);
            *(ushort4*)(ps + l15 * 72 + g * 16 + quad * 4) = pk;
        }
#pragma unroll
        for (int f = 0; f < 4; f++) {
            o[f][0] *= alpha; o[f][1] *= alpha;
            o[f][2] *= alpha; o[f][3] *= alpha;
        }
        // P^T B-frags (col=q l15, keys quad*8 / +32)
        short8 pf0 = *(const short8*)(ps + l15 * 72 + quad * 8);
        short8 pf1 = *(const short8*)(ps + l15 * 72 + 32 + quad * 8);
        const unsigned short* vbb = &Vblob[b][0];
#pragma unroll
        for (int f = 0; f < 4; f++) {
            short8 vf0 = *(const short8*)(vbb + (f * 2 + 0) * 512 + lane * 8);
            short8 vf1 = *(const short8*)(vbb + (f * 2 + 1) * 512 + lane * 8);
            o[f] = __builtin_amdgcn_mfma_f32_16x16x32_bf16(vf0, pf0, o[f], 0, 0, 0);
            o[f] = __builtin_amdgcn_mfma_f32_16x16x32_bf16(vf1, pf1, o[f], 0, 0, 0);
        }
    }

    // final l reduction across quads, then un-transpose O^T via LDS
    lv += __shfl_xor(lv, 16);
    lv += __shfl_xor(lv, 32);
    float inv = 1.0f / lv;
    __syncthreads();  // safe reuse of Ps region
#pragma unroll
    for (int f = 0; f < 4; f++) {
        ushort4 pk;
        pk.x = f2b(o[f][0] * inv);
        pk.y = f2b(o[f][1] * inv);
        pk.z = f2b(o[f][2] * inv);
        pk.w = f2b(o[f][3] * inv);
        *(ushort4*)(ps + l15 * 72 + f * 16 + quad * 4) = pk;  // row=q, d=f*16+quad*4
    }
    short8 r0 = *(const short8*)(ps + l15 * 72 + quad * 8);
    short8 r1 = *(const short8*)(ps + l15 * 72 + 32 + quad * 8);
    size_t obase = (size_t)(bb * S_LEN + qbase + l15) * DMODEL + h * DK;
    *(short8*)(O + obase + quad * 8) = r0;
    *(short8*)(O + obase + 32 + quad * 8) = r1;
}

// ---------------------------------------------------------------------------
extern "C" void kernel_launch(void* const* d_in, const int* in_sizes, int n_in,
                              void* d_out, int out_size, void* d_ws,
                              size_t ws_size, hipStream_t stream) {
    const float* x = (const float*)d_in[0];
    const float* Wq = (const float*)d_in[1];
    const float* Wk = (const float*)d_in[2];
    const float* Wv = (const float*)d_in[3];
    const float* Wo = (const float*)d_in[4];
    const int* tokpos = (const int*)d_in[5];
    float* out = (float*)d_out;

    const size_t MD = (size_t)MTOT * DMODEL;  // 4194304
    const size_t WD = (size_t)DMODEL * DMODEL;
    unsigned short* xb = (unsigned short*)d_ws;
    unsigned short* Wqt = xb + MD;
    unsigned short* Wkt = Wqt + WD;
    unsigned short* Wvt = Wkt + WD;
    unsigned short* Wot = Wvt + WD;
    unsigned short* Q = Wot + WD;
    unsigned short* K = Q + MD;
    unsigned short* Vt = K + MD;  // [b*1024 + d][s] — written directly by mm_k
    unsigned short* O = Vt + MD;
    float* ct = (float*)(O + MD);
    float* st = ct + S_LEN * 32;

    // fused preprocessing: cast + rope tables + weight transposes
    prep_k<<<dim3(3328), dim3(256), 0, stream>>>(x, xb, tokpos, ct, st,
                                                 Wq, Wk, Wv, Wo, Wqt, Wkt, Wvt, Wot);

    // Q (RoPE*0.125), K (RoPE), Vt (transposed store); grid x=m for XCD A-reuse
    mm_k<<<dim3(32, 8, 3), dim3(256), 0, stream>>>(xb, Wqt, Wkt, Wvt,
                                                   (void*)Q, (void*)K, (void*)Vt, ct, st, 0);
    attn_k<<<dim3(512), dim3(512), 0, stream>>>(Q, K, Vt, O);
    // output projection, fp32 store
    mm_k<<<dim3(32, 8, 1), dim3(256), 0, stream>>>(O, Wot, Wot, Wot,
                                                   (void*)out, (void*)out, (void*)out, ct, st, 1);
}

// Round 10
// 220.068 us; speedup vs baseline: 1.0371x; 1.0371x over previous
//
#include <hip/hip_runtime.h>
#include <hip/hip_bf16.h>
#include <cmath>

#define S_LEN 2048
#define DMODEL 1024
#define NHEADS 16
#define DK 64
#define BATCH 2
#define MTOT (BATCH * S_LEN) /* 4096 */

using short8 = __attribute__((ext_vector_type(8))) short;
using floatx4 = __attribute__((ext_vector_type(4))) float;

// float -> bf16 bits, round-to-nearest-even (scalar path)
__device__ __forceinline__ unsigned short f2b(float f) {
    union { float f; unsigned u; } v; v.f = f;
    unsigned r = v.u + 0x7fff + ((v.u >> 16) & 1);
    return (unsigned short)(r >> 16);
}

// packed 2x float -> bf16x2 (v_cvt_pk_bf16_f32)
__device__ __forceinline__ unsigned pack2(float a, float b) {
    float2 t; t.x = a; t.y = b;
    __hip_bfloat162 h = __float22bfloat162_rn(t);
    union { __hip_bfloat162 h; unsigned u; } v; v.h = h;
    return v.u;
}

// async global->LDS, 16 B/lane. LDS dest is wave-uniform base (+lane*16 by HW).
__device__ __forceinline__ void gload16(const void* g, void* l) {
    __builtin_amdgcn_global_load_lds(
        (const __attribute__((address_space(1))) unsigned int*)g,
        (__attribute__((address_space(3))) unsigned int*)l, 16, 0, 0);
}

// ---------------------------------------------------------------------------
// Fused preprocessing (single dispatch, blockIdx-range partition):
//   blocks [0, 2048)        : x fp32 -> bf16 cast
//   blocks [2048, 2304)     : RoPE cos/sin tables
//   blocks [2304, 3328)     : W fp32 [k][n] -> bf16 [n][k] transpose
//                             (Wq,Wk head-dims permuted: d -> d/2 or 32+d/2)
// ---------------------------------------------------------------------------
__global__ __launch_bounds__(256) void prep_k(
    const float* __restrict__ x, unsigned short* __restrict__ xb,
    const int* __restrict__ tokpos, float* __restrict__ ct, float* __restrict__ st,
    const float* W0, const float* W1, const float* W2, const float* W3,
    unsigned short* T0, unsigned short* T1, unsigned short* T2, unsigned short* T3) {
    __shared__ float t[64][65];
    const int b = blockIdx.x;
    if (b < 2048) {
        int i = (b * 256 + threadIdx.x) * 8;
        float4 a = *(const float4*)(x + i);
        float4 bb = *(const float4*)(x + i + 4);
        short8 o;
        o[0] = f2b(a.x); o[1] = f2b(a.y); o[2] = f2b(a.z); o[3] = f2b(a.w);
        o[4] = f2b(bb.x); o[5] = f2b(bb.y); o[6] = f2b(bb.z); o[7] = f2b(bb.w);
        *(short8*)(xb + i) = o;
    } else if (b < 2304) {
        int idx = (b - 2048) * 256 + threadIdx.x;  // 0 .. 2048*32-1
        int si = idx >> 5;
        int ip = idx & 31;
        float pos = (float)tokpos[si];
        float inv_freq = powf(10000.0f, -(float)(2 * ip) / 64.0f);
        float ang = pos * inv_freq;
        ct[idx] = cosf(ang);
        st[idx] = sinf(ang);
    } else {
        int id = b - 2304;          // 0..1023
        int z = id >> 8;            // matrix
        int bx = id & 15, by = (id >> 4) & 15;
        const float* W = z == 0 ? W0 : z == 1 ? W1 : z == 2 ? W2 : W3;
        unsigned short* T = z == 0 ? T0 : z == 1 ? T1 : z == 2 ? T2 : T3;
        const bool perm = (z < 2);
        int n0 = bx * 64, k0 = by * 64;
        int rr = threadIdx.x >> 6, cc = threadIdx.x & 63;
#pragma unroll
        for (int r = 0; r < 16; r++) {
            int row = r * 4 + rr;
            t[row][cc] = W[(size_t)(k0 + row) * DMODEL + n0 + cc];
        }
        __syncthreads();
#pragma unroll
        for (int r = 0; r < 16; r++) {
            int row = r * 4 + rr;  // original col within head
            int drow = perm ? (((row & 1) ? 32 : 0) + (row >> 1)) : row;
            T[(size_t)(n0 + drow) * DMODEL + k0 + cc] = f2b(t[cc][row]);
        }
    }
}

// ---------------------------------------------------------------------------
// V[s][d] bf16 -> Vt[b*1024 + d][s] bf16, 64x64 LDS tiles
// ---------------------------------------------------------------------------
__global__ __launch_bounds__(256) void vtrans_k(const unsigned short* __restrict__ V,
                                                unsigned short* __restrict__ Vt) {
    __shared__ unsigned short t[64][72];  // 144 B rows: 16B-aligned, bank-spread
    const int tid = threadIdx.x;
    const int s0 = blockIdx.x * 64, d0 = blockIdx.y * 64;
    const int bb = s0 >> 11;
#pragma unroll
    for (int it = 0; it < 4; it++) {
        int e = (it * 256 + tid) * 4;  // flat ushort4 id: row=s, col=d
        int r = e >> 6, c = e & 63;
        *(ushort4*)&t[r][c] = *(const ushort4*)(V + (size_t)(s0 + r) * DMODEL + d0 + c);
    }
    __syncthreads();
#pragma unroll
    for (int it = 0; it < 4; it++) {
        int e = (it * 256 + tid) * 4;  // flat ushort4 id: row=d, col=s
        int r = e >> 6, c = e & 63;
        ushort4 v;
        v.x = t[c + 0][r]; v.y = t[c + 1][r];
        v.z = t[c + 2][r]; v.w = t[c + 3][r];
        *(ushort4*)(Vt + (size_t)(bb * 1024 + d0 + r) * S_LEN + (s0 & (S_LEN - 1)) + c) = v;
    }
}

// ---------------------------------------------------------------------------
// bf16 MFMA GEMM: C[4096,1024] = A[4096,1024] x Bt^T  (Bt is [N][K] bf16)
// 128x128 tile, BK=32, 4 waves, 4x4 mfma. Grid (x=m, y=n, z): XCD A-reuse.
// (R9's fused-Vt epilogue regressed 55->73 us — reverted to R7 shape.)
// kind 0: z<2 -> RoPE (permuted-d weights, shuffle-free) bf16; Q (z==0)
//   scaled by 0.125/ln2 (1/sqrt(dk) + exp2-domain softmax) folded into c/s;
//   z==2 -> plain bf16 store (V).
// kind 1: plain fp32 store (final output).
// ---------------------------------------------------------------------------
__global__ __launch_bounds__(256) void mm_k(
    const unsigned short* __restrict__ A,
    const unsigned short* __restrict__ Bt0, const unsigned short* __restrict__ Bt1,
    const unsigned short* __restrict__ Bt2,
    void* C0, void* C1, void* C2,
    const float* __restrict__ ct, const float* __restrict__ st, int kind) {
    __shared__ __align__(16) unsigned short blob[8192];  // 16 KB: A 8K + B 8K bytes

    const int z = blockIdx.z;
    const unsigned short* Bt = z == 0 ? Bt0 : z == 1 ? Bt1 : Bt2;
    void* C = z == 0 ? C0 : z == 1 ? C1 : C2;
    const int mode = (kind == 1) ? 0 : (z == 2 ? 3 : 1);
    // 0.125/ln2: QK^T scaling + exp2-domain softmax, folded into Q
    const float qscale = (z == 0 && kind == 0) ? 0.18033688011112042f : 1.0f;

    const int tid = threadIdx.x;
    const int w = tid >> 6, lane = tid & 63;
    const int l15 = lane & 15, quad = lane >> 4;
    const int wr = w >> 1, wc = w & 1;
    const int m0 = blockIdx.x * 128, n0 = blockIdx.y * 128;  // x=m: XCD A-reuse

    floatx4 acc[4][4];
#pragma unroll
    for (int i = 0; i < 4; i++)
#pragma unroll
        for (int j = 0; j < 4; j++) acc[i][j] = (floatx4){0.f, 0.f, 0.f, 0.f};

    for (int k0 = 0; k0 < DMODEL; k0 += 32) {
        if (k0) __syncthreads();
#pragma unroll
        for (int it = 0; it < 4; it++) {
            int g = it * 4 + w;  // wave-uniform group 0..15 (A: 0..7, B: 8..15)
            const unsigned short* gp;
            if (g < 8)
                gp = A + (size_t)(m0 + g * 16 + l15) * DMODEL + k0 + (lane >> 4) * 8;
            else
                gp = Bt + (size_t)(n0 + (g - 8) * 16 + l15) * DMODEL + k0 + (lane >> 4) * 8;
            gload16(gp, (char*)blob + g * 1024);
        }
        __syncthreads();

        short8 af[4], bfr[4];
#pragma unroll
        for (int i = 0; i < 4; i++)
            af[i] = *(const short8*)((char*)blob + ((wr * 4 + i) * 64 + lane) * 16);
#pragma unroll
        for (int j = 0; j < 4; j++)
            bfr[j] = *(const short8*)((char*)blob + 8192 + ((wc * 4 + j) * 64 + lane) * 16);
#pragma unroll
        for (int i = 0; i < 4; i++)
#pragma unroll
            for (int j = 0; j < 4; j++)
                acc[i][j] = __builtin_amdgcn_mfma_f32_16x16x32_bf16(af[i], bfr[j], acc[i][j], 0, 0, 0);
    }

    // epilogue: C/D layout col = l15, row = quad*4 + reg
#pragma unroll
    for (int i = 0; i < 4; i++) {
        const int rowb = m0 + wr * 64 + i * 16 + quad * 4;
        if (mode == 0) {
            float* Cf = (float*)C;
#pragma unroll
            for (int j = 0; j < 4; j++) {
                int colb = n0 + wc * 64 + j * 16 + l15;
#pragma unroll
                for (int r = 0; r < 4; r++)
                    Cf[(size_t)(rowb + r) * DMODEL + colb] = acc[i][j][r];
            }
        } else if (mode == 1) {
            unsigned short* Cb = (unsigned short*)C;
#pragma unroll
            for (int jh = 0; jh < 2; jh++) {
                int ip = jh * 16 + l15;                   // pair index within head
                int cole = n0 + wc * 64 + jh * 16 + l15;  // even-member column (d'<32)
#pragma unroll
                for (int r = 0; r < 4; r++) {
                    int row = rowb + r;
                    int si = row & (S_LEN - 1);
                    float c = ct[si * 32 + ip] * qscale;
                    float s = st[si * 32 + ip] * qscale;
                    float e = acc[i][jh][r];       // x_even (permuted weights)
                    float od = acc[i][jh + 2][r];  // x_odd (partner col, same thread)
                    Cb[(size_t)row * DMODEL + cole] = f2b(e * c - od * s);
                    Cb[(size_t)row * DMODEL + cole + 32] = f2b(e * s + od * c);
                }
            }
        } else {
            unsigned short* Cb = (unsigned short*)C;
#pragma unroll
            for (int j = 0; j < 4; j++) {
                int colb = n0 + wc * 64 + j * 16 + l15;
#pragma unroll
                for (int r = 0; r < 4; r++)
                    Cb[(size_t)(rowb + r) * DMODEL + colb] = f2b(acc[i][j][r]);
            }
        }
    }
}

// ---------------------------------------------------------------------------
// Block-cooperative MFMA flash attention, 64-key tiles, 128-query blocks.
// Grid 512 = (16 q-tiles x 32 bh), longest first; 8 waves (512 thr), each
// wave owns 16 queries. One staged K/V tile feeds 8 waves. Double-buffered
// LDS via global_load_lds, 1 barrier per tile. Q pre-scaled by 0.125/ln2 ->
// exp2-domain online softmax (no per-score multiply). Wave-uniform causal
// fast path skips mask selects on interior tiles. Packed bf16 cvt for P/O.
// ---------------------------------------------------------------------------
__global__ __launch_bounds__(512) void attn_k(const unsigned short* __restrict__ Q,
                                              const unsigned short* __restrict__ K,
                                              const unsigned short* __restrict__ Vt,
                                              unsigned short* __restrict__ O) {
    __shared__ __align__(16) unsigned short Kblob[2][4096];  // 8 KB/buf
    __shared__ __align__(16) unsigned short Vblob[2][4096];
    __shared__ __align__(16) unsigned short Ps[8][16 * 72];  // per-wave P / O-bounce

    const int tid = threadIdx.x;
    const int w = tid >> 6, lane = tid & 63;
    const int l15 = lane & 15, quad = lane >> 4;
    const int idx = blockIdx.x;
    const int qt = 15 - (idx >> 5);  // longest blocks dispatch first
    const int bh = idx & 31;
    const int bb = bh >> 4, h = bh & 15;
    const int qbase = qt * 128 + w * 16;
    const int qrow = qbase + l15;

    // Q fragment (B-operand: col=query=l15, k=quad*8), d-halves 0/1
    const size_t qoff = (size_t)(bb * S_LEN + qbase + l15) * DMODEL + h * DK;
    short8 aq0 = *(const short8*)(Q + qoff + quad * 8);
    short8 aq1 = *(const short8*)(Q + qoff + 32 + quad * 8);

    floatx4 o[4];
#pragma unroll
    for (int f = 0; f < 4; f++) o[f] = (floatx4){0.f, 0.f, 0.f, 0.f};
    float mv = -1e30f, lv = 0.f;

    const unsigned short* Kb = K + (size_t)(bb * S_LEN) * DMODEL + h * DK;
    const unsigned short* Vb = Vt + (size_t)(bb * 1024 + h * DK) * S_LEN;
    unsigned short* ps = &Ps[w][0];

    // stage 64-key K/V tile into blob buffer b (2 gload16/thread, 8 waves)
    auto stage = [&](int b, int kb) {
#pragma unroll
        for (int it = 0; it < 2; it++) {
            int g = it * 8 + w;  // wave-uniform 0..15; 0..7 K-groups, 8..15 V-groups
            if (g < 8) {
                const unsigned short* gp =
                    Kb + (size_t)(kb + (g >> 1) * 16 + l15) * DMODEL + (g & 1) * 32 + quad * 8;
                gload16(gp, (char*)&Kblob[b][0] + g * 1024);
            } else {
                int gv = g - 8;
                const unsigned short* gp =
                    Vb + (size_t)((gv >> 1) * 16 + l15) * S_LEN + kb + (gv & 1) * 32 + quad * 8;
                gload16(gp, (char*)&Vblob[b][0] + gv * 1024);
            }
        }
    };

    const int nkt = 2 * qt + 2;  // key tiles covering 0..qt*128+127, uniform
    stage(0, 0);
    for (int kt = 0; kt < nkt; kt++) {
        const int b = kt & 1;
        const int kb = kt * 64;
        __syncthreads();  // staging of buf b complete; buf b^1 reads done
        if (kt + 1 < nkt) stage(b ^ 1, (kt + 1) * 64);

        // QK^T: S^T[key 64][q 16]
        const unsigned short* kbb = &Kblob[b][0];
        floatx4 c[4];
#pragma unroll
        for (int g = 0; g < 4; g++) {
            short8 kf0 = *(const short8*)(kbb + (g * 2 + 0) * 512 + lane * 8);
            short8 kf1 = *(const short8*)(kbb + (g * 2 + 1) * 512 + lane * 8);
            floatx4 t = {0.f, 0.f, 0.f, 0.f};
            t = __builtin_amdgcn_mfma_f32_16x16x32_bf16(kf0, aq0, t, 0, 0, 0);
            c[g] = __builtin_amdgcn_mfma_f32_16x16x32_bf16(kf1, aq1, t, 0, 0, 0);
        }

        // softmax over 16 keys/lane (exp2 domain; scores pre-scaled via Q)
        float sv[16];
        if (kb + 63 <= qbase) {  // wave-uniform: whole tile causal-valid
#pragma unroll
            for (int g = 0; g < 4; g++)
#pragma unroll
                for (int r = 0; r < 4; r++) sv[g * 4 + r] = c[g][r];
        } else {
#pragma unroll
            for (int g = 0; g < 4; g++)
#pragma unroll
                for (int r = 0; r < 4; r++) {
                    int key = kb + g * 16 + quad * 4 + r;
                    sv[g * 4 + r] = (key <= qrow) ? c[g][r] : -1e30f;
                }
        }
        float mx = sv[0];
#pragma unroll
        for (int i = 1; i < 16; i++) mx = fmaxf(mx, sv[i]);
        mx = fmaxf(mx, __shfl_xor(mx, 16));
        mx = fmaxf(mx, __shfl_xor(mx, 32));
        float mnew = fmaxf(mv, mx);
        float alpha = exp2f(mv - mnew);
        mv = mnew;
        float p[16], psum = 0.f;
#pragma unroll
        for (int i = 0; i < 16; i++) {
            p[i] = exp2f(sv[i] - mnew);
            psum += p[i];
        }
        lv = lv * alpha + psum;  // per-lane partial; cross-quad reduce at end

        // P -> LDS (row=q l15, key = g*16+quad*4..+3), stride 72 shorts
#pragma unroll
        for (int g = 0; g < 4; g++) {
            uint2 pk;
            pk.x = pack2(p[g * 4 + 0], p[g * 4 + 1]);
            pk.y = pack2(p[g * 4 + 2], p[g * 4 + 3]);
            *(uint2*)(ps + l15 * 72 + g * 16 + quad * 4) = pk;
        }
#pragma unroll
        for (int f = 0; f < 4; f++) {
            o[f][0] *= alpha; o[f][1] *= alpha;
            o[f][2] *= alpha; o[f][3] *= alpha;
        }
        // P^T B-frags (col=q l15, keys quad*8 / +32)
        short8 pf0 = *(const short8*)(ps + l15 * 72 + quad * 8);
        short8 pf1 = *(const short8*)(ps + l15 * 72 + 32 + quad * 8);
        const unsigned short* vbb = &Vblob[b][0];
#pragma unroll
        for (int f = 0; f < 4; f++) {
            short8 vf0 = *(const short8*)(vbb + (f * 2 + 0) * 512 + lane * 8);
            short8 vf1 = *(const short8*)(vbb + (f * 2 + 1) * 512 + lane * 8);
            o[f] = __builtin_amdgcn_mfma_f32_16x16x32_bf16(vf0, pf0, o[f], 0, 0, 0);
            o[f] = __builtin_amdgcn_mfma_f32_16x16x32_bf16(vf1, pf1, o[f], 0, 0, 0);
        }
    }

    // final l reduction across quads, then un-transpose O^T via LDS
    lv += __shfl_xor(lv, 16);
    lv += __shfl_xor(lv, 32);
    float inv = 1.0f / lv;
    __syncthreads();  // safe reuse of Ps region
#pragma unroll
    for (int f = 0; f < 4; f++) {
        uint2 pk;
        pk.x = pack2(o[f][0] * inv, o[f][1] * inv);
        pk.y = pack2(o[f][2] * inv, o[f][3] * inv);
        *(uint2*)(ps + l15 * 72 + f * 16 + quad * 4) = pk;  // row=q, d=f*16+quad*4
    }
    short8 r0 = *(const short8*)(ps + l15 * 72 + quad * 8);
    short8 r1 = *(const short8*)(ps + l15 * 72 + 32 + quad * 8);
    size_t obase = (size_t)(bb * S_LEN + qbase + l15) * DMODEL + h * DK;
    *(short8*)(O + obase + quad * 8) = r0;
    *(short8*)(O + obase + 32 + quad * 8) = r1;
}

// ---------------------------------------------------------------------------
extern "C" void kernel_launch(void* const* d_in, const int* in_sizes, int n_in,
                              void* d_out, int out_size, void* d_ws,
                              size_t ws_size, hipStream_t stream) {
    const float* x = (const float*)d_in[0];
    const float* Wq = (const float*)d_in[1];
    const float* Wk = (const float*)d_in[2];
    const float* Wv = (const float*)d_in[3];
    const float* Wo = (const float*)d_in[4];
    const int* tokpos = (const int*)d_in[5];
    float* out = (float*)d_out;

    const size_t MD = (size_t)MTOT * DMODEL;  // 4194304
    const size_t WD = (size_t)DMODEL * DMODEL;
    unsigned short* xb = (unsigned short*)d_ws;
    unsigned short* Wqt = xb + MD;
    unsigned short* Wkt = Wqt + WD;
    unsigned short* Wvt = Wkt + WD;
    unsigned short* Wot = Wvt + WD;
    unsigned short* Q = Wot + WD;
    unsigned short* K = Q + MD;
    unsigned short* V = K + MD;   // after vtrans, reused as attention output O
    unsigned short* Vt = V + MD;  // [b*1024 + d][s]
    float* ct = (float*)(Vt + MD);
    float* st = ct + S_LEN * 32;
    unsigned short* O = V;  // alias: V dead after vtrans_k

    // fused preprocessing: cast + rope tables + weight transposes
    prep_k<<<dim3(3328), dim3(256), 0, stream>>>(x, xb, tokpos, ct, st,
                                                 Wq, Wk, Wv, Wo, Wqt, Wkt, Wvt, Wot);

    // Q (RoPE * 0.125/ln2), K (RoPE), V (plain bf16); grid x=m for XCD A-reuse
    mm_k<<<dim3(32, 8, 3), dim3(256), 0, stream>>>(xb, Wqt, Wkt, Wvt,
                                                   (void*)Q, (void*)K, (void*)V, ct, st, 0);
    vtrans_k<<<dim3(64, 16), dim3(256), 0, stream>>>(V, Vt);
    attn_k<<<dim3(512), dim3(512), 0, stream>>>(Q, K, Vt, O);
    // output projection, fp32 store
    mm_k<<<dim3(32, 8, 1), dim3(256), 0, stream>>>(O, Wot, Wot, Wot,
                                                   (void*)out, (void*)out, (void*)out, ct, st, 1);
}

// Round 11
// 210.989 us; speedup vs baseline: 1.0817x; 1.0430x over previous
//
#include <hip/hip_runtime.h>
#include <hip/hip_bf16.h>
#include <cmath>

#define S_LEN 2048
#define DMODEL 1024
#define NHEADS 16
#define DK 64
#define BATCH 2
#define MTOT (BATCH * S_LEN) /* 4096 */

using short8 = __attribute__((ext_vector_type(8))) short;
using floatx4 = __attribute__((ext_vector_type(4))) float;

// float -> bf16 bits, round-to-nearest-even (scalar path)
__device__ __forceinline__ unsigned short f2b(float f) {
    union { float f; unsigned u; } v; v.f = f;
    unsigned r = v.u + 0x7fff + ((v.u >> 16) & 1);
    return (unsigned short)(r >> 16);
}

// packed 2x float -> bf16x2 (v_cvt_pk_bf16_f32)
__device__ __forceinline__ unsigned pack2(float a, float b) {
    float2 t; t.x = a; t.y = b;
    __hip_bfloat162 h = __float22bfloat162_rn(t);
    union { __hip_bfloat162 h; unsigned u; } v; v.h = h;
    return v.u;
}

// async global->LDS, 16 B/lane. LDS dest is wave-uniform base (+lane*16 by HW).
__device__ __forceinline__ void gload16(const void* g, void* l) {
    __builtin_amdgcn_global_load_lds(
        (const __attribute__((address_space(1))) unsigned int*)g,
        (__attribute__((address_space(3))) unsigned int*)l, 16, 0, 0);
}

// ---------------------------------------------------------------------------
// Fused preprocessing (single dispatch, blockIdx-range partition):
//   blocks [0, 2048)        : x fp32 -> bf16 cast
//   blocks [2048, 2304)     : RoPE cos/sin tables
//   blocks [2304, 3328)     : W fp32 [k][n] -> bf16 [n][k] transpose
//                             (Wq,Wk head-dims permuted: d -> d/2 or 32+d/2)
// ---------------------------------------------------------------------------
__global__ __launch_bounds__(256) void prep_k(
    const float* __restrict__ x, unsigned short* __restrict__ xb,
    const int* __restrict__ tokpos, float* __restrict__ ct, float* __restrict__ st,
    const float* W0, const float* W1, const float* W2, const float* W3,
    unsigned short* T0, unsigned short* T1, unsigned short* T2, unsigned short* T3) {
    __shared__ float t[64][65];
    const int b = blockIdx.x;
    if (b < 2048) {
        int i = (b * 256 + threadIdx.x) * 8;
        float4 a = *(const float4*)(x + i);
        float4 bb = *(const float4*)(x + i + 4);
        short8 o;
        o[0] = f2b(a.x); o[1] = f2b(a.y); o[2] = f2b(a.z); o[3] = f2b(a.w);
        o[4] = f2b(bb.x); o[5] = f2b(bb.y); o[6] = f2b(bb.z); o[7] = f2b(bb.w);
        *(short8*)(xb + i) = o;
    } else if (b < 2304) {
        int idx = (b - 2048) * 256 + threadIdx.x;  // 0 .. 2048*32-1
        int si = idx >> 5;
        int ip = idx & 31;
        float pos = (float)tokpos[si];
        float inv_freq = powf(10000.0f, -(float)(2 * ip) / 64.0f);
        float ang = pos * inv_freq;
        ct[idx] = cosf(ang);
        st[idx] = sinf(ang);
    } else {
        int id = b - 2304;          // 0..1023
        int z = id >> 8;            // matrix
        int bx = id & 15, by = (id >> 4) & 15;
        const float* W = z == 0 ? W0 : z == 1 ? W1 : z == 2 ? W2 : W3;
        unsigned short* T = z == 0 ? T0 : z == 1 ? T1 : z == 2 ? T2 : T3;
        const bool perm = (z < 2);
        int n0 = bx * 64, k0 = by * 64;
        int rr = threadIdx.x >> 6, cc = threadIdx.x & 63;
#pragma unroll
        for (int r = 0; r < 16; r++) {
            int row = r * 4 + rr;
            t[row][cc] = W[(size_t)(k0 + row) * DMODEL + n0 + cc];
        }
        __syncthreads();
#pragma unroll
        for (int r = 0; r < 16; r++) {
            int row = r * 4 + rr;  // original col within head
            int drow = perm ? (((row & 1) ? 32 : 0) + (row >> 1)) : row;
            T[(size_t)(n0 + drow) * DMODEL + k0 + cc] = f2b(t[cc][row]);
        }
    }
}

// ---------------------------------------------------------------------------
// V[s][d] bf16 -> Vt[b*1024 + d][s] bf16, 64x64 LDS tiles
// ---------------------------------------------------------------------------
__global__ __launch_bounds__(256) void vtrans_k(const unsigned short* __restrict__ V,
                                                unsigned short* __restrict__ Vt) {
    __shared__ unsigned short t[64][72];  // 144 B rows: 16B-aligned, bank-spread
    const int tid = threadIdx.x;
    const int s0 = blockIdx.x * 64, d0 = blockIdx.y * 64;
    const int bb = s0 >> 11;
#pragma unroll
    for (int it = 0; it < 4; it++) {
        int e = (it * 256 + tid) * 4;  // flat ushort4 id: row=s, col=d
        int r = e >> 6, c = e & 63;
        *(ushort4*)&t[r][c] = *(const ushort4*)(V + (size_t)(s0 + r) * DMODEL + d0 + c);
    }
    __syncthreads();
#pragma unroll
    for (int it = 0; it < 4; it++) {
        int e = (it * 256 + tid) * 4;  // flat ushort4 id: row=d, col=s
        int r = e >> 6, c = e & 63;
        ushort4 v;
        v.x = t[c + 0][r]; v.y = t[c + 1][r];
        v.z = t[c + 2][r]; v.w = t[c + 3][r];
        *(ushort4*)(Vt + (size_t)(bb * 1024 + d0 + r) * S_LEN + (s0 & (S_LEN - 1)) + c) = v;
    }
}

// ---------------------------------------------------------------------------
// bf16 MFMA GEMM: C[4096,1024] = A[4096,1024] x Bt^T  (Bt is [N][K] bf16)
// 128x128 tile, BK=32, 4 waves, 4x4 mfma. Grid (x=m, y=n, z): XCD A-reuse.
// DOUBLE-BUFFERED staging (attn_k-style): barrier -> stage(next tile into
// buf^1) -> compute(current buf). One barrier/iter; staging latency overlaps
// the 16-MFMA compute phase. (R10 counters: stage->barrier->compute exposed
// ~4100 cyc/iter of load latency — Wo GEMM at 1 block/CU ran as slow as QKV
// at 3 blocks/CU.) LDS 32 KB (5 blocks/CU cap, grid needs <=3).
// kind 0: z<2 -> RoPE (permuted-d weights, shuffle-free) bf16; Q (z==0)
//   scaled by 0.125/ln2 (1/sqrt(dk) + exp2-domain softmax) folded into c/s;
//   z==2 -> plain bf16 store (V).
// kind 1: plain fp32 store (final output).
// ---------------------------------------------------------------------------
__global__ __launch_bounds__(256) void mm_k(
    const unsigned short* __restrict__ A,
    const unsigned short* __restrict__ Bt0, const unsigned short* __restrict__ Bt1,
    const unsigned short* __restrict__ Bt2,
    void* C0, void* C1, void* C2,
    const float* __restrict__ ct, const float* __restrict__ st, int kind) {
    // per buffer: A groups bytes [0,8192), B groups bytes [8192,16384)
    __shared__ __align__(16) unsigned short blob[2][8192];

    const int z = blockIdx.z;
    const unsigned short* Bt = z == 0 ? Bt0 : z == 1 ? Bt1 : Bt2;
    void* C = z == 0 ? C0 : z == 1 ? C1 : C2;
    const int mode = (kind == 1) ? 0 : (z == 2 ? 3 : 1);
    // 0.125/ln2: QK^T scaling + exp2-domain softmax, folded into Q
    const float qscale = (z == 0 && kind == 0) ? 0.18033688011112042f : 1.0f;

    const int tid = threadIdx.x;
    const int w = tid >> 6, lane = tid & 63;
    const int l15 = lane & 15, quad = lane >> 4;
    const int wr = w >> 1, wc = w & 1;
    const int m0 = blockIdx.x * 128, n0 = blockIdx.y * 128;  // x=m: XCD A-reuse

    floatx4 acc[4][4];
#pragma unroll
    for (int i = 0; i < 4; i++)
#pragma unroll
        for (int j = 0; j < 4; j++) acc[i][j] = (floatx4){0.f, 0.f, 0.f, 0.f};

    // stage one 128x32 A-tile + 128x32 B-tile into buffer buf
    auto stage = [&](int buf, int k0) {
#pragma unroll
        for (int it = 0; it < 4; it++) {
            int g = it * 4 + w;  // wave-uniform group 0..15 (A: 0..7, B: 8..15)
            const unsigned short* gp;
            if (g < 8)
                gp = A + (size_t)(m0 + g * 16 + l15) * DMODEL + k0 + quad * 8;
            else
                gp = Bt + (size_t)(n0 + (g - 8) * 16 + l15) * DMODEL + k0 + quad * 8;
            gload16(gp, (char*)&blob[buf][0] + g * 1024);
        }
    };

    stage(0, 0);
    for (int kt = 0; kt < DMODEL / 32; kt++) {
        const int b = kt & 1;
        __syncthreads();  // staging of buf b complete; prior reads of b^1 done
        if (kt + 1 < DMODEL / 32) stage(b ^ 1, (kt + 1) * 32);

        const char* base = (const char*)&blob[b][0];
        short8 af[4], bfr[4];
#pragma unroll
        for (int i = 0; i < 4; i++)
            af[i] = *(const short8*)(base + ((wr * 4 + i) * 64 + lane) * 16);
#pragma unroll
        for (int j = 0; j < 4; j++)
            bfr[j] = *(const short8*)(base + 8192 + ((wc * 4 + j) * 64 + lane) * 16);
#pragma unroll
        for (int i = 0; i < 4; i++)
#pragma unroll
            for (int j = 0; j < 4; j++)
                acc[i][j] = __builtin_amdgcn_mfma_f32_16x16x32_bf16(af[i], bfr[j], acc[i][j], 0, 0, 0);
    }

    // epilogue: C/D layout col = l15, row = quad*4 + reg
#pragma unroll
    for (int i = 0; i < 4; i++) {
        const int rowb = m0 + wr * 64 + i * 16 + quad * 4;
        if (mode == 0) {
            float* Cf = (float*)C;
#pragma unroll
            for (int j = 0; j < 4; j++) {
                int colb = n0 + wc * 64 + j * 16 + l15;
#pragma unroll
                for (int r = 0; r < 4; r++)
                    Cf[(size_t)(rowb + r) * DMODEL + colb] = acc[i][j][r];
            }
        } else if (mode == 1) {
            unsigned short* Cb = (unsigned short*)C;
#pragma unroll
            for (int jh = 0; jh < 2; jh++) {
                int ip = jh * 16 + l15;                   // pair index within head
                int cole = n0 + wc * 64 + jh * 16 + l15;  // even-member column (d'<32)
#pragma unroll
                for (int r = 0; r < 4; r++) {
                    int row = rowb + r;
                    int si = row & (S_LEN - 1);
                    float c = ct[si * 32 + ip] * qscale;
                    float s = st[si * 32 + ip] * qscale;
                    float e = acc[i][jh][r];       // x_even (permuted weights)
                    float od = acc[i][jh + 2][r];  // x_odd (partner col, same thread)
                    Cb[(size_t)row * DMODEL + cole] = f2b(e * c - od * s);
                    Cb[(size_t)row * DMODEL + cole + 32] = f2b(e * s + od * c);
                }
            }
        } else {
            unsigned short* Cb = (unsigned short*)C;
#pragma unroll
            for (int j = 0; j < 4; j++) {
                int colb = n0 + wc * 64 + j * 16 + l15;
#pragma unroll
                for (int r = 0; r < 4; r++)
                    Cb[(size_t)(rowb + r) * DMODEL + colb] = f2b(acc[i][j][r]);
            }
        }
    }
}

// ---------------------------------------------------------------------------
// Block-cooperative MFMA flash attention, 64-key tiles, 128-query blocks.
// Grid 512 = (16 q-tiles x 32 bh), longest first; 8 waves (512 thr), each
// wave owns 16 queries. One staged K/V tile feeds 8 waves. Double-buffered
// LDS via global_load_lds, 1 barrier per tile. Q pre-scaled by 0.125/ln2 ->
// exp2-domain online softmax. Wave-uniform causal fast path on interior
// tiles. Packed bf16 cvt for P/O.
// ---------------------------------------------------------------------------
__global__ __launch_bounds__(512) void attn_k(const unsigned short* __restrict__ Q,
                                              const unsigned short* __restrict__ K,
                                              const unsigned short* __restrict__ Vt,
                                              unsigned short* __restrict__ O) {
    __shared__ __align__(16) unsigned short Kblob[2][4096];  // 8 KB/buf
    __shared__ __align__(16) unsigned short Vblob[2][4096];
    __shared__ __align__(16) unsigned short Ps[8][16 * 72];  // per-wave P / O-bounce

    const int tid = threadIdx.x;
    const int w = tid >> 6, lane = tid & 63;
    const int l15 = lane & 15, quad = lane >> 4;
    const int idx = blockIdx.x;
    const int qt = 15 - (idx >> 5);  // longest blocks dispatch first
    const int bh = idx & 31;
    const int bb = bh >> 4, h = bh & 15;
    const int qbase = qt * 128 + w * 16;
    const int qrow = qbase + l15;

    // Q fragment (B-operand: col=query=l15, k=quad*8), d-halves 0/1
    const size_t qoff = (size_t)(bb * S_LEN + qbase + l15) * DMODEL + h * DK;
    short8 aq0 = *(const short8*)(Q + qoff + quad * 8);
    short8 aq1 = *(const short8*)(Q + qoff + 32 + quad * 8);

    floatx4 o[4];
#pragma unroll
    for (int f = 0; f < 4; f++) o[f] = (floatx4){0.f, 0.f, 0.f, 0.f};
    float mv = -1e30f, lv = 0.f;

    const unsigned short* Kb = K + (size_t)(bb * S_LEN) * DMODEL + h * DK;
    const unsigned short* Vb = Vt + (size_t)(bb * 1024 + h * DK) * S_LEN;
    unsigned short* ps = &Ps[w][0];

    // stage 64-key K/V tile into blob buffer b (2 gload16/thread, 8 waves)
    auto stage = [&](int b, int kb) {
#pragma unroll
        for (int it = 0; it < 2; it++) {
            int g = it * 8 + w;  // wave-uniform 0..15; 0..7 K-groups, 8..15 V-groups
            if (g < 8) {
                const unsigned short* gp =
                    Kb + (size_t)(kb + (g >> 1) * 16 + l15) * DMODEL + (g & 1) * 32 + quad * 8;
                gload16(gp, (char*)&Kblob[b][0] + g * 1024);
            } else {
                int gv = g - 8;
                const unsigned short* gp =
                    Vb + (size_t)((gv >> 1) * 16 + l15) * S_LEN + kb + (gv & 1) * 32 + quad * 8;
                gload16(gp, (char*)&Vblob[b][0] + gv * 1024);
            }
        }
    };

    const int nkt = 2 * qt + 2;  // key tiles covering 0..qt*128+127, uniform
    stage(0, 0);
    for (int kt = 0; kt < nkt; kt++) {
        const int b = kt & 1;
        const int kb = kt * 64;
        __syncthreads();  // staging of buf b complete; buf b^1 reads done
        if (kt + 1 < nkt) stage(b ^ 1, (kt + 1) * 64);

        // QK^T: S^T[key 64][q 16]
        const unsigned short* kbb = &Kblob[b][0];
        floatx4 c[4];
#pragma unroll
        for (int g = 0; g < 4; g++) {
            short8 kf0 = *(const short8*)(kbb + (g * 2 + 0) * 512 + lane * 8);
            short8 kf1 = *(const short8*)(kbb + (g * 2 + 1) * 512 + lane * 8);
            floatx4 t = {0.f, 0.f, 0.f, 0.f};
            t = __builtin_amdgcn_mfma_f32_16x16x32_bf16(kf0, aq0, t, 0, 0, 0);
            c[g] = __builtin_amdgcn_mfma_f32_16x16x32_bf16(kf1, aq1, t, 0, 0, 0);
        }

        // softmax over 16 keys/lane (exp2 domain; scores pre-scaled via Q)
        float sv[16];
        if (kb + 63 <= qbase) {  // wave-uniform: whole tile causal-valid
#pragma unroll
            for (int g = 0; g < 4; g++)
#pragma unroll
                for (int r = 0; r < 4; r++) sv[g * 4 + r] = c[g][r];
        } else {
#pragma unroll
            for (int g = 0; g < 4; g++)
#pragma unroll
                for (int r = 0; r < 4; r++) {
                    int key = kb + g * 16 + quad * 4 + r;
                    sv[g * 4 + r] = (key <= qrow) ? c[g][r] : -1e30f;
                }
        }
        float mx = sv[0];
#pragma unroll
        for (int i = 1; i < 16; i++) mx = fmaxf(mx, sv[i]);
        mx = fmaxf(mx, __shfl_xor(mx, 16));
        mx = fmaxf(mx, __shfl_xor(mx, 32));
        float mnew = fmaxf(mv, mx);
        float alpha = exp2f(mv - mnew);
        mv = mnew;
        float p[16], psum = 0.f;
#pragma unroll
        for (int i = 0; i < 16; i++) {
            p[i] = exp2f(sv[i] - mnew);
            psum += p[i];
        }
        lv = lv * alpha + psum;  // per-lane partial; cross-quad reduce at end

        // P -> LDS (row=q l15, key = g*16+quad*4..+3), stride 72 shorts
#pragma unroll
        for (int g = 0; g < 4; g++) {
            uint2 pk;
            pk.x = pack2(p[g * 4 + 0], p[g * 4 + 1]);
            pk.y = pack2(p[g * 4 + 2], p[g * 4 + 3]);
            *(uint2*)(ps + l15 * 72 + g * 16 + quad * 4) = pk;
        }
#pragma unroll
        for (int f = 0; f < 4; f++) {
            o[f][0] *= alpha; o[f][1] *= alpha;
            o[f][2] *= alpha; o[f][3] *= alpha;
        }
        // P^T B-frags (col=q l15, keys quad*8 / +32)
        short8 pf0 = *(const short8*)(ps + l15 * 72 + quad * 8);
        short8 pf1 = *(const short8*)(ps + l15 * 72 + 32 + quad * 8);
        const unsigned short* vbb = &Vblob[b][0];
#pragma unroll
        for (int f = 0; f < 4; f++) {
            short8 vf0 = *(const short8*)(vbb + (f * 2 + 0) * 512 + lane * 8);
            short8 vf1 = *(const short8*)(vbb + (f * 2 + 1) * 512 + lane * 8);
            o[f] = __builtin_amdgcn_mfma_f32_16x16x32_bf16(vf0, pf0, o[f], 0, 0, 0);
            o[f] = __builtin_amdgcn_mfma_f32_16x16x32_bf16(vf1, pf1, o[f], 0, 0, 0);
        }
    }

    // final l reduction across quads, then un-transpose O^T via LDS
    lv += __shfl_xor(lv, 16);
    lv += __shfl_xor(lv, 32);
    float inv = 1.0f / lv;
    __syncthreads();  // safe reuse of Ps region
#pragma unroll
    for (int f = 0; f < 4; f++) {
        uint2 pk;
        pk.x = pack2(o[f][0] * inv, o[f][1] * inv);
        pk.y = pack2(o[f][2] * inv, o[f][3] * inv);
        *(uint2*)(ps + l15 * 72 + f * 16 + quad * 4) = pk;  // row=q, d=f*16+quad*4
    }
    short8 r0 = *(const short8*)(ps + l15 * 72 + quad * 8);
    short8 r1 = *(const short8*)(ps + l15 * 72 + 32 + quad * 8);
    size_t obase = (size_t)(bb * S_LEN + qbase + l15) * DMODEL + h * DK;
    *(short8*)(O + obase + quad * 8) = r0;
    *(short8*)(O + obase + 32 + quad * 8) = r1;
}

// ---------------------------------------------------------------------------
extern "C" void kernel_launch(void* const* d_in, const int* in_sizes, int n_in,
                              void* d_out, int out_size, void* d_ws,
                              size_t ws_size, hipStream_t stream) {
    const float* x = (const float*)d_in[0];
    const float* Wq = (const float*)d_in[1];
    const float* Wk = (const float*)d_in[2];
    const float* Wv = (const float*)d_in[3];
    const float* Wo = (const float*)d_in[4];
    const int* tokpos = (const int*)d_in[5];
    float* out = (float*)d_out;

    const size_t MD = (size_t)MTOT * DMODEL;  // 4194304
    const size_t WD = (size_t)DMODEL * DMODEL;
    unsigned short* xb = (unsigned short*)d_ws;
    unsigned short* Wqt = xb + MD;
    unsigned short* Wkt = Wqt + WD;
    unsigned short* Wvt = Wkt + WD;
    unsigned short* Wot = Wvt + WD;
    unsigned short* Q = Wot + WD;
    unsigned short* K = Q + MD;
    unsigned short* V = K + MD;   // after vtrans, reused as attention output O
    unsigned short* Vt = V + MD;  // [b*1024 + d][s]
    float* ct = (float*)(Vt + MD);
    float* st = ct + S_LEN * 32;
    unsigned short* O = V;  // alias: V dead after vtrans_k

    // fused preprocessing: cast + rope tables + weight transposes
    prep_k<<<dim3(3328), dim3(256), 0, stream>>>(x, xb, tokpos, ct, st,
                                                 Wq, Wk, Wv, Wo, Wqt, Wkt, Wvt, Wot);

    // Q (RoPE * 0.125/ln2), K (RoPE), V (plain bf16); grid x=m for XCD A-reuse
    mm_k<<<dim3(32, 8, 3), dim3(256), 0, stream>>>(xb, Wqt, Wkt, Wvt,
                                                   (void*)Q, (void*)K, (void*)V, ct, st, 0);
    vtrans_k<<<dim3(64, 16), dim3(256), 0, stream>>>(V, Vt);
    attn_k<<<dim3(512), dim3(512), 0, stream>>>(Q, K, Vt, O);
    // output projection, fp32 store
    mm_k<<<dim3(32, 8, 1), dim3(256), 0, stream>>>(O, Wot, Wot, Wot,
                                                   (void*)out, (void*)out, (void*)out, ct, st, 1);
}